// Round 2
// baseline (1334.031 us; speedup 1.0000x reference)
//
#include <hip/hip_runtime.h>
#include <math.h>

#define BM 64        // tokens per block
#define BK 32        // K chunk
#define TN 256       // padded candidate count
#define D_DIM 2048
#define T_N 245
#define TOPK 8
#define SXPAD 36     // x tile LDS row stride (floats)

// LDS layout (union, 16384 floats = 64 KB exactly -> 2 blocks/CU):
//   staging phase: sw[BK][TN] at [0,8192), sx[BM][SXPAD] at [8192,10496)
//   epilogue:      exp values, swizzled rows: smem[r*256 + ((c + r) & 255)]
__global__ __launch_bounds__(256, 2)
void router_fused(const float* __restrict__ x,
                  const float* __restrict__ Wr,
                  const float* __restrict__ br,
                  const int*   __restrict__ conn,
                  float* __restrict__ out_x,
                  float* __restrict__ out_p,
                  float* __restrict__ out_n,
                  unsigned char* __restrict__ flags)
{
    __shared__ float smem[16384];

    const int tid = threadIdx.x;
    const int tr = tid >> 4;            // 0..15 (row group)
    const int tc = tid & 15;            // 0..15 (col group)
    const long row0 = (long)blockIdx.x * BM;

    float acc[4][16];
#pragma unroll
    for (int j = 0; j < 4; ++j)
#pragma unroll
        for (int c = 0; c < 16; ++c) acc[j][c] = 0.0f;

    const int xr = tid >> 2;            // 0..63 (staging row)
    const int xp = tid & 3;             // 0..3  (k-part)

    for (int k0 = 0; k0 < D_DIM; k0 += BK) {
        __syncthreads();  // previous compute done before restaging

        // ---- stage W[k0..k0+31][0..244] into sw (stride-256 rows) ----
        {
            const float4* wsrc = reinterpret_cast<const float4*>(Wr + (long)k0 * T_N);
            for (int i4 = tid; i4 < (BK * T_N) / 4; i4 += 256) {  // 1960 float4s
                float4 v = wsrc[i4];
                int flat = i4 * 4;
                int r = (int)(((unsigned)flat * 68480u) >> 24);   // flat / 245
                int c = flat - r * 245;
                float vv[4] = {v.x, v.y, v.z, v.w};
#pragma unroll
                for (int e = 0; e < 4; ++e) {
                    int cc = c + e, rr = r;
                    if (cc >= T_N) { cc -= T_N; rr += 1; }
                    smem[rr * TN + cc] = vv[e];
                }
            }
        }
        // ---- stage x tile + passthrough copy to out_x ----
        {
            const float* src = x + (row0 + xr) * (long)D_DIM + k0 + xp * 8;
            float4 v0 = *reinterpret_cast<const float4*>(src);
            float4 v1 = *reinterpret_cast<const float4*>(src + 4);
            float* dst = out_x + (row0 + xr) * (long)D_DIM + k0 + xp * 8;
            *reinterpret_cast<float4*>(dst)     = v0;
            *reinterpret_cast<float4*>(dst + 4) = v1;
            float vv[8] = {v0.x, v0.y, v0.z, v0.w, v1.x, v1.y, v1.z, v1.w};
#pragma unroll
            for (int i = 0; i < 8; ++i)
                smem[8192 + xr * SXPAD + xp * 8 + i] = vv[i];
        }
        __syncthreads();

        // ---- compute: acc += x_tile * W_tile ----
#pragma unroll
        for (int kq = 0; kq < BK / 4; ++kq) {
            float4 a4[4];
#pragma unroll
            for (int j = 0; j < 4; ++j)
                a4[j] = *reinterpret_cast<const float4*>(
                    &smem[8192 + (tr * 4 + j) * SXPAD + kq * 4]);
#pragma unroll
            for (int u = 0; u < 4; ++u) {
                const int kk = kq * 4 + u;
                float4 b4[4];
#pragma unroll
                for (int g = 0; g < 4; ++g)
                    b4[g] = *reinterpret_cast<const float4*>(
                        &smem[kk * TN + g * 64 + tc * 4]);
#pragma unroll
                for (int j = 0; j < 4; ++j) {
                    const float av = reinterpret_cast<const float*>(&a4[j])[u];
#pragma unroll
                    for (int g = 0; g < 4; ++g) {
                        acc[j][g * 4 + 0] = fmaf(av, b4[g].x, acc[j][g * 4 + 0]);
                        acc[j][g * 4 + 1] = fmaf(av, b4[g].y, acc[j][g * 4 + 1]);
                        acc[j][g * 4 + 2] = fmaf(av, b4[g].z, acc[j][g * 4 + 2]);
                        acc[j][g * 4 + 3] = fmaf(av, b4[g].w, acc[j][g * 4 + 3]);
                    }
                }
            }
        }
    }

    __syncthreads();  // all staging reads done before logit buffer overwrite

    // ---- write logits (+bias) to swizzled buffer ----
#pragma unroll
    for (int j = 0; j < 4; ++j) {
        const int row = tr * 4 + j;
#pragma unroll
        for (int g = 0; g < 4; ++g) {
#pragma unroll
            for (int e = 0; e < 4; ++e) {
                const int col = g * 64 + tc * 4 + e;
                float v = acc[j][g * 4 + e];
                if (col < T_N) v += br[col];
                smem[row * 256 + ((col + row) & 255)] = v;
            }
        }
    }
    __syncthreads();

    // ---- per-row softmax + top-8 (one thread per row) ----
    if (tid < BM) {
        const int r = tid;
        const long gr = row0 + r;
        float* base = &smem[r * 256];
        // max (4 interleaved chains)
        float m0 = -INFINITY, m1 = -INFINITY, m2 = -INFINITY, m3 = -INFINITY;
        for (int t = 0; t < 244; t += 4) {
            m0 = fmaxf(m0, base[(t + 0 + r) & 255]);
            m1 = fmaxf(m1, base[(t + 1 + r) & 255]);
            m2 = fmaxf(m2, base[(t + 2 + r) & 255]);
            m3 = fmaxf(m3, base[(t + 3 + r) & 255]);
        }
        m0 = fmaxf(m0, base[(244 + r) & 255]);
        const float m = fmaxf(fmaxf(m0, m1), fmaxf(m2, m3));
        // exp + sum, store exp in place (exp is monotone in logit ->
        // argmax on exp values == argmax on logits)
        float s0 = 0.f, s1 = 0.f, s2 = 0.f, s3 = 0.f;
        for (int t = 0; t < 244; t += 4) {
            float e0 = expf(base[(t + 0 + r) & 255] - m); base[(t + 0 + r) & 255] = e0; s0 += e0;
            float e1 = expf(base[(t + 1 + r) & 255] - m); base[(t + 1 + r) & 255] = e1; s1 += e1;
            float e2 = expf(base[(t + 2 + r) & 255] - m); base[(t + 2 + r) & 255] = e2; s2 += e2;
            float e3 = expf(base[(t + 3 + r) & 255] - m); base[(t + 3 + r) & 255] = e3; s3 += e3;
        }
        { float e = expf(base[(244 + r) & 255] - m); base[(244 + r) & 255] = e; s0 += e; }
        const float inv = 1.0f / ((s0 + s1) + (s2 + s3));
        // 9 masked arg-max passes (8 outputs + 1 gap probe),
        // lowest-index tie-break (lax.top_k semantics).
        float prev = INFINITY;
        int flag = 0;
#pragma unroll 1
        for (int k = 0; k < TOPK + 1; ++k) {
            float b0 = -1.f, b1 = -1.f, b2 = -1.f, b3 = -1.f;
            int i0 = 0, i1 = 0, i2 = 0, i3 = 0;
            for (int t = 0; t < 244; t += 4) {
                float v0 = base[(t + 0 + r) & 255];
                float v1 = base[(t + 1 + r) & 255];
                float v2 = base[(t + 2 + r) & 255];
                float v3 = base[(t + 3 + r) & 255];
                if (v0 > b0) { b0 = v0; i0 = t; }
                if (v1 > b1) { b1 = v1; i1 = t + 1; }
                if (v2 > b2) { b2 = v2; i2 = t + 2; }
                if (v3 > b3) { b3 = v3; i3 = t + 3; }
            }
            { float v = base[(244 + r) & 255]; if (v > b0) { b0 = v; i0 = 244; } }
            float best = b0; int bi = i0;
            if (b1 > best || (b1 == best && i1 < bi)) { best = b1; bi = i1; }
            if (b2 > best || (b2 == best && i2 < bi)) { best = b2; bi = i2; }
            if (b3 > best || (b3 == best && i3 < bi)) { best = b3; bi = i3; }
            // near-tie detection: relative exp ratio == logit gap < 2e-4
            if (best >= prev * 0.9998f) flag = 1;
            prev = best;
            if (k < TOPK) {
                base[(bi + r) & 255] = -1.f;  // mask selected
                out_p[gr * TOPK + k] = best * inv;
                const int* cp = conn + bi * 3;
                out_n[(gr * TOPK + k) * 3 + 0] = (float)cp[0];
                out_n[(gr * TOPK + k) * 3 + 1] = (float)cp[1];
                out_n[(gr * TOPK + k) * 3 + 2] = (float)cp[2];
            }
        }
        flags[gr] = (unsigned char)flag;
    }
}

// Phase 2: fp64 recompute of softmax+top-8 for flagged (near-tie) tokens.
// fp32*fp32 products are exact in fp64; sequential fp64 sum error ~1e-13,
// far below any plausible true logit gap -> ordering matches the fp64 ref.
__global__ __launch_bounds__(256)
void refine_fp64(const float* __restrict__ x,
                 const float* __restrict__ Wr,
                 const float* __restrict__ br,
                 const int*   __restrict__ conn,
                 float* __restrict__ out_p,
                 float* __restrict__ out_n,
                 const unsigned char* __restrict__ flags)
{
    __shared__ float  sx[D_DIM];
    __shared__ double sl[256];   // logits
    __shared__ double se[256];   // exp values
    __shared__ double smax;

    const int tid = threadIdx.x;
    const long tok0 = (long)blockIdx.x * BM;

    for (int ti = 0; ti < BM; ++ti) {
        const long tok = tok0 + ti;
        if (!flags[tok]) continue;      // uniform across block

        // stage x row (2048 floats)
        {
            const float4* src = reinterpret_cast<const float4*>(x + tok * D_DIM);
            for (int i = tid; i < D_DIM / 4; i += 256) {
                float4 v = src[i];
                sx[i * 4 + 0] = v.x; sx[i * 4 + 1] = v.y;
                sx[i * 4 + 2] = v.z; sx[i * 4 + 3] = v.w;
            }
        }
        __syncthreads();

        double acc = 0.0;
        if (tid < T_N) {
            const float* wp = Wr + tid;
#pragma unroll 4
            for (int k = 0; k < D_DIM; ++k)
                acc += (double)sx[k] * (double)wp[(long)k * T_N];
            acc += (double)br[tid];
        }
        sl[tid] = (tid < T_N) ? acc : -1.0e300;
        __syncthreads();

        if (tid == 0) {
            double mm = -1.0e300;
            for (int t = 0; t < T_N; ++t) mm = (sl[t] > mm) ? sl[t] : mm;
            smax = mm;
        }
        __syncthreads();
        se[tid] = (tid < T_N) ? exp(sl[tid] - smax) : 0.0;
        __syncthreads();

        if (tid == 0) {
            double Z = 0.0;
            for (int t = 0; t < T_N; ++t) Z += se[t];
            const double invZ = 1.0 / Z;
            for (int k = 0; k < TOPK; ++k) {
                double best = -1.0; int bi = 0;
                for (int t = 0; t < T_N; ++t)
                    if (se[t] > best) { best = se[t]; bi = t; }
                se[bi] = -1.0;
                out_p[tok * TOPK + k] = (float)(best * invZ);
                const int* cp = conn + bi * 3;
                out_n[(tok * TOPK + k) * 3 + 0] = (float)cp[0];
                out_n[(tok * TOPK + k) * 3 + 1] = (float)cp[1];
                out_n[(tok * TOPK + k) * 3 + 2] = (float)cp[2];
            }
        }
        __syncthreads();   // before smem reuse for next token
    }
}

extern "C" void kernel_launch(void* const* d_in, const int* in_sizes, int n_in,
                              void* d_out, int out_size, void* d_ws, size_t ws_size,
                              hipStream_t stream) {
    const float* x    = (const float*)d_in[0];
    const float* Wr   = (const float*)d_in[1];
    const float* br   = (const float*)d_in[2];
    const int*   conn = (const int*)d_in[3];
    // d_in[4] = top_k (always 8; geometry is static)

    float* out_x = (float*)d_out;                                   // [8,4096,2048]
    float* out_p = out_x + (size_t)8 * 4096 * 2048;                 // [8,4096,8]
    float* out_n = out_p + (size_t)8 * 4096 * 8;                    // [8,4096,8,3] as float

    unsigned char* flags = (unsigned char*)d_ws;                    // 32768 bytes

    const int num_rows = 8 * 4096;                                  // 32768
    dim3 grid(num_rows / BM), block(256);
    hipLaunchKernelGGL(router_fused, grid, block, 0, stream,
                       x, Wr, br, conn, out_x, out_p, out_n, flags);
    hipLaunchKernelGGL(refine_fp64, grid, block, 0, stream,
                       x, Wr, br, conn, out_p, out_n, flags);
}

// Round 3
// 1171.722 us; speedup vs baseline: 1.1385x; 1.1385x over previous
//
#include <hip/hip_runtime.h>
#include <math.h>

#define D_DIM 2048
#define T_N   245
#define TOPK  8
#define BM    128
#define BK    64
#define NCH   (D_DIM / BK)     // 32
#define LDA   72               // LDS row stride in bf16 elems (144 B)

typedef __attribute__((ext_vector_type(8))) __bf16 bf16x8;
typedef __attribute__((ext_vector_type(4))) float  f32x4;

// ws layout (needs ~2.3 MB):
//   [0]                : unsigned counter
//   [256 ..]           : token list, unsigned[32768]  (128 KB)
//   [256K ..]          : WT_hi bf16 [256][2048]  (1 MB)
//   [256K+1M ..]       : WT_lo bf16 [256][2048]  (1 MB)
#define WS_LIST_OFF   256
#define WS_WTHI_OFF   (256 * 1024)
#define WS_WTLO_OFF   (256 * 1024 + 1024 * 1024)

__device__ __forceinline__ unsigned short bf16_rne(float f) {
    unsigned u = __builtin_bit_cast(unsigned, f);
    u += 0x7FFFu + ((u >> 16) & 1u);
    return (unsigned short)(u >> 16);
}
__device__ __forceinline__ float bf16_to_f(unsigned short h) {
    return __builtin_bit_cast(float, (unsigned)h << 16);
}

// ---------------------------------------------------------------------------
// Prep: W [2048][245] fp32  ->  WT_hi/WT_lo [256][2048] bf16 (transposed,
// split hi/lo, cols 245..255 zero). Also zeroes the flag counter.
// ---------------------------------------------------------------------------
__global__ __launch_bounds__(256)
void prep_wt(const float* __restrict__ W,
             unsigned* __restrict__ cnt,
             unsigned short* __restrict__ wt_hi,
             unsigned short* __restrict__ wt_lo)
{
    if (blockIdx.x == 0 && blockIdx.y == 0 && threadIdx.x == 0) *cnt = 0u;

    __shared__ float tile[64][65];
    const int r0 = blockIdx.x * 64;      // k tile (32 tiles)
    const int c0 = blockIdx.y * 64;      // n tile (4 tiles)
    const int tid = threadIdx.x;

    {
        const int j = tid & 63, ib = tid >> 6;
#pragma unroll
        for (int s = 0; s < 16; ++s) {
            const int i = ib * 16 + s;
            const int c = c0 + j;
            tile[i][j] = (c < T_N) ? W[(long)(r0 + i) * T_N + c] : 0.0f;
        }
    }
    __syncthreads();
    {
        const int ii = tid & 63, jb = tid >> 6;
#pragma unroll
        for (int s = 0; s < 16; ++s) {
            const int jj = jb * 16 + s;
            const float f = tile[ii][jj];
            const unsigned short h = bf16_rne(f);
            const unsigned short l = bf16_rne(f - bf16_to_f(h));
            const long o = (long)(c0 + jj) * D_DIM + (r0 + ii);
            wt_hi[o] = h;
            wt_lo[o] = l;
        }
    }
}

// ---------------------------------------------------------------------------
// Main: split-bf16 MFMA GEMM (x[128 rows] x W[245]) + x passthrough +
// softmax + top-8 + near-tie flagging.  1 block/CU, 8 waves, dynamic LDS.
// ---------------------------------------------------------------------------
#define ISSUE_LOADS(c)                                                          \
    {                                                                           \
        const int k0_ = (c) * BK;                                               \
        for (int s = 0; s < 4; ++s)                                             \
            la[s] = *reinterpret_cast<const float4*>(                           \
                x + (row0 + arow + 32 * s) * (long)D_DIM + k0_ + acol);         \
        for (int s = 0; s < 4; ++s) {                                           \
            const long bo_ = (long)(bn + 64 * s) * D_DIM + k0_ + bk8;           \
            lbh[s] = *reinterpret_cast<const float4*>(wt_hi + bo_);             \
            lbl[s] = *reinterpret_cast<const float4*>(wt_lo + bo_);             \
        }                                                                       \
    }

__global__ __launch_bounds__(512, 2)
void router_mfma(const float* __restrict__ x,
                 const unsigned short* __restrict__ wt_hi,
                 const unsigned short* __restrict__ wt_lo,
                 const float* __restrict__ br,
                 const int*   __restrict__ conn,
                 float* __restrict__ out_x,
                 float* __restrict__ out_p,
                 float* __restrict__ out_n,
                 unsigned* __restrict__ cnt,
                 unsigned* __restrict__ list)
{
    extern __shared__ char smem[];
    unsigned short* Ah = (unsigned short*)(smem);            // [128][72] bf16
    unsigned short* Al = (unsigned short*)(smem + 18432);
    unsigned short* Bh = (unsigned short*)(smem + 36864);    // [256][72] bf16
    unsigned short* Bl = (unsigned short*)(smem + 73728);
    float* slog = (float*)smem;                              // epilogue [128][256]

    const int tid = threadIdx.x;
    const long row0 = (long)blockIdx.x * BM;

    // staging assignments
    const int arow = tid >> 4;           // 0..31 (+32s) : x rows
    const int acol = (tid & 15) * 4;     // fp32 k-offset within chunk
    const int bn   = tid >> 3;           // 0..63 (+64s) : WT rows
    const int bk8  = (tid & 7) * 8;      // bf16 k-offset within chunk

    // wave tiling
    const int lane = tid & 63;
    const int wid  = tid >> 6;
    const int wr   = wid >> 2;           // 0..1
    const int wc   = wid & 3;            // 0..3
    const int m16  = lane & 15;
    const int k8   = (lane >> 4) * 8;

    f32x4 acc[4][4];
#pragma unroll
    for (int fr = 0; fr < 4; ++fr)
#pragma unroll
        for (int fc = 0; fc < 4; ++fc)
            acc[fr][fc] = (f32x4){0.f, 0.f, 0.f, 0.f};

    float4 la[4], lbh[4], lbl[4];
    ISSUE_LOADS(0)

    for (int c = 0; c < NCH; ++c) {
        const int k0 = c * BK;
        // ---- stage chunk c from regs into LDS (+ x passthrough) ----
#pragma unroll
        for (int s = 0; s < 4; ++s) {
            const int r = arow + 32 * s;
            const float* f = reinterpret_cast<const float*>(&la[s]);
            unsigned short h[4], l[4];
#pragma unroll
            for (int e = 0; e < 4; ++e) {
                h[e] = bf16_rne(f[e]);
                l[e] = bf16_rne(f[e] - bf16_to_f(h[e]));
            }
            uint2 uh = make_uint2((unsigned)h[0] | ((unsigned)h[1] << 16),
                                  (unsigned)h[2] | ((unsigned)h[3] << 16));
            uint2 ul = make_uint2((unsigned)l[0] | ((unsigned)l[1] << 16),
                                  (unsigned)l[2] | ((unsigned)l[3] << 16));
            *reinterpret_cast<uint2*>(&Ah[r * LDA + acol]) = uh;
            *reinterpret_cast<uint2*>(&Al[r * LDA + acol]) = ul;
            *reinterpret_cast<float4*>(out_x + (row0 + r) * (long)D_DIM + k0 + acol) = la[s];
        }
#pragma unroll
        for (int s = 0; s < 4; ++s) {
            const int n = bn + 64 * s;
            *reinterpret_cast<float4*>(&Bh[n * LDA + bk8]) = lbh[s];
            *reinterpret_cast<float4*>(&Bl[n * LDA + bk8]) = lbl[s];
        }
        __syncthreads();

        if (c + 1 < NCH) ISSUE_LOADS(c + 1)   // overlap next loads with MFMA

        // ---- compute: 3 sub-passes (hi*hi, hi*lo, lo*hi) over 2 k-steps ----
#pragma unroll
        for (int ks = 0; ks < 2; ++ks) {
            const int kb = ks * 32 + k8;
            bf16x8 ah[4], bh[4], t[4];
#pragma unroll
            for (int fr = 0; fr < 4; ++fr)
                ah[fr] = *reinterpret_cast<const bf16x8*>(
                    &Ah[(wr * 64 + fr * 16 + m16) * LDA + kb]);
#pragma unroll
            for (int fc = 0; fc < 4; ++fc)
                bh[fc] = *reinterpret_cast<const bf16x8*>(
                    &Bh[(wc * 64 + fc * 16 + m16) * LDA + kb]);
#pragma unroll
            for (int fr = 0; fr < 4; ++fr)
#pragma unroll
                for (int fc = 0; fc < 4; ++fc)
                    acc[fr][fc] = __builtin_amdgcn_mfma_f32_16x16x32_bf16(
                        ah[fr], bh[fc], acc[fr][fc], 0, 0, 0);
#pragma unroll
            for (int fc = 0; fc < 4; ++fc)
                t[fc] = *reinterpret_cast<const bf16x8*>(
                    &Bl[(wc * 64 + fc * 16 + m16) * LDA + kb]);
#pragma unroll
            for (int fr = 0; fr < 4; ++fr)
#pragma unroll
                for (int fc = 0; fc < 4; ++fc)
                    acc[fr][fc] = __builtin_amdgcn_mfma_f32_16x16x32_bf16(
                        ah[fr], t[fc], acc[fr][fc], 0, 0, 0);
#pragma unroll
            for (int fr = 0; fr < 4; ++fr)
                t[fr] = *reinterpret_cast<const bf16x8*>(
                    &Al[(wr * 64 + fr * 16 + m16) * LDA + kb]);
#pragma unroll
            for (int fr = 0; fr < 4; ++fr)
#pragma unroll
                for (int fc = 0; fc < 4; ++fc)
                    acc[fr][fc] = __builtin_amdgcn_mfma_f32_16x16x32_bf16(
                        t[fr], bh[fc], acc[fr][fc], 0, 0, 0);
        }
        __syncthreads();
    }

    // ---- epilogue: logits -> swizzled LDS (reuses staging LDS) ----
#pragma unroll
    for (int fr = 0; fr < 4; ++fr)
#pragma unroll
        for (int fc = 0; fc < 4; ++fc)
#pragma unroll
            for (int r = 0; r < 4; ++r) {
                const int row = wr * 64 + fr * 16 + ((lane >> 4) << 2) + r;
                const int col = wc * 64 + fc * 16 + m16;
                float v = acc[fr][fc][r];
                v = (col < T_N) ? v + br[col] : -1e30f;
                slog[row * 256 + ((col + row) & 255)] = v;
            }
    __syncthreads();

    // ---- per-row softmax + top-8 + near-tie flag (one thread per row) ----
    if (tid < BM) {
        const int r = tid;
        const long gr = row0 + r;
        float* base = &slog[r * 256];
        float m0 = -INFINITY, m1 = -INFINITY, m2 = -INFINITY, m3 = -INFINITY;
        for (int t = 0; t < 244; t += 4) {
            m0 = fmaxf(m0, base[(t + 0 + r) & 255]);
            m1 = fmaxf(m1, base[(t + 1 + r) & 255]);
            m2 = fmaxf(m2, base[(t + 2 + r) & 255]);
            m3 = fmaxf(m3, base[(t + 3 + r) & 255]);
        }
        m0 = fmaxf(m0, base[(244 + r) & 255]);
        const float m = fmaxf(fmaxf(m0, m1), fmaxf(m2, m3));
        float s0 = 0.f, s1 = 0.f, s2 = 0.f, s3 = 0.f;
        for (int t = 0; t < 244; t += 4) {
            float e0 = expf(base[(t + 0 + r) & 255] - m); base[(t + 0 + r) & 255] = e0; s0 += e0;
            float e1 = expf(base[(t + 1 + r) & 255] - m); base[(t + 1 + r) & 255] = e1; s1 += e1;
            float e2 = expf(base[(t + 2 + r) & 255] - m); base[(t + 2 + r) & 255] = e2; s2 += e2;
            float e3 = expf(base[(t + 3 + r) & 255] - m); base[(t + 3 + r) & 255] = e3; s3 += e3;
        }
        { float e = expf(base[(244 + r) & 255] - m); base[(244 + r) & 255] = e; s0 += e; }
        const float inv = 1.0f / ((s0 + s1) + (s2 + s3));
        float prev = INFINITY;
        int flag = 0;
#pragma unroll 1
        for (int k = 0; k < TOPK + 1; ++k) {
            float b0 = -1.f, b1 = -1.f, b2 = -1.f, b3 = -1.f;
            int i0 = 0, i1 = 0, i2 = 0, i3 = 0;
            for (int t = 0; t < 244; t += 4) {
                float v0 = base[(t + 0 + r) & 255];
                float v1 = base[(t + 1 + r) & 255];
                float v2 = base[(t + 2 + r) & 255];
                float v3 = base[(t + 3 + r) & 255];
                if (v0 > b0) { b0 = v0; i0 = t; }
                if (v1 > b1) { b1 = v1; i1 = t + 1; }
                if (v2 > b2) { b2 = v2; i2 = t + 2; }
                if (v3 > b3) { b3 = v3; i3 = t + 3; }
            }
            { float v = base[(244 + r) & 255]; if (v > b0) { b0 = v; i0 = 244; } }
            float best = b0; int bi = i0;
            if (b1 > best || (b1 == best && i1 < bi)) { best = b1; bi = i1; }
            if (b2 > best || (b2 == best && i2 < bi)) { best = b2; bi = i2; }
            if (b3 > best || (b3 == best && i3 < bi)) { best = b3; bi = i3; }
            if (best >= prev * 0.9998f) flag = 1;   // logit gap < 2e-4
            prev = best;
            if (k < TOPK) {
                base[(bi + r) & 255] = -1.f;
                out_p[gr * TOPK + k] = best * inv;
                const int* cp = conn + bi * 3;
                out_n[(gr * TOPK + k) * 3 + 0] = (float)cp[0];
                out_n[(gr * TOPK + k) * 3 + 1] = (float)cp[1];
                out_n[(gr * TOPK + k) * 3 + 2] = (float)cp[2];
            }
        }
        if (flag) {
            unsigned idx = atomicAdd(cnt, 1u);
            if (idx < 32768u) list[idx] = (unsigned)gr;
        }
    }
}

// ---------------------------------------------------------------------------
// Refine: fp64 recompute for flagged tokens. 4 tokens/block share W reads;
// wave-parallel softmax+top-8 (no serial thread).
// ---------------------------------------------------------------------------
#define RB 4
__global__ __launch_bounds__(256)
void refine_fp64(const float* __restrict__ x,
                 const float* __restrict__ W,
                 const float* __restrict__ br,
                 const int*   __restrict__ conn,
                 float* __restrict__ out_p,
                 float* __restrict__ out_n,
                 const unsigned* __restrict__ cnt,
                 const unsigned* __restrict__ list)
{
    __shared__ float  sx[RB][D_DIM];   // 32 KB
    __shared__ double sl[RB][256];     // 8 KB

    const int tid = threadIdx.x;
    const unsigned count = min(*cnt, 32768u);

    for (unsigned b0 = blockIdx.x * RB; b0 < count; b0 += gridDim.x * RB) {
        const int nb = (int)min((unsigned)RB, count - b0);
        // stage x rows
        for (int j = 0; j < RB; ++j) {
            if (j >= nb) break;
            const long tok = (long)list[b0 + j];
            const float4* src = reinterpret_cast<const float4*>(x + tok * D_DIM);
            for (int i = tid; i < D_DIM / 4; i += 256)
                *reinterpret_cast<float4*>(&sx[j][i * 4]) = src[i];
        }
        __syncthreads();

        // logits (fp64), W reads shared across the 4 tokens
        if (tid < T_N) {
            double a0 = 0, a1 = 0, a2 = 0, a3 = 0;
            const float* wp = W + tid;
#pragma unroll 8
            for (int k = 0; k < D_DIM; ++k) {
                const double w = (double)wp[(long)k * T_N];
                a0 += (double)sx[0][k] * w;
                a1 += (double)sx[1][k] * w;
                a2 += (double)sx[2][k] * w;
                a3 += (double)sx[3][k] * w;
            }
            const double bb = (double)br[tid];
            sl[0][tid] = a0 + bb; sl[1][tid] = a1 + bb;
            sl[2][tid] = a2 + bb; sl[3][tid] = a3 + bb;
        }
        __syncthreads();

        // wave w handles token (b0 + w)
        const int w = tid >> 6, lane = tid & 63;
        if (w < nb) {
            const long tok = (long)list[b0 + w];
            double v[4];
#pragma unroll
            for (int i = 0; i < 4; ++i) {
                const int t = lane + 64 * i;
                v[i] = (t < T_N) ? sl[w][t] : -1.0e300;
            }
            double m = fmax(fmax(v[0], v[1]), fmax(v[2], v[3]));
#pragma unroll
            for (int off = 32; off >= 1; off >>= 1)
                m = fmax(m, __shfl_xor(m, off));
            double e[4]; double s = 0.0;
#pragma unroll
            for (int i = 0; i < 4; ++i) {
                const int t = lane + 64 * i;
                e[i] = (t < T_N) ? exp(sl[w][t] - m) : 0.0;
                s += e[i];
            }
#pragma unroll
            for (int off = 32; off >= 1; off >>= 1)
                s += __shfl_xor(s, off);
            const double invZ = 1.0 / s;

            int sel[TOPK];
#pragma unroll
            for (int k = 0; k < TOPK; ++k) {
                double bv = -1.0; int bi = 255;
#pragma unroll
                for (int i = 0; i < 4; ++i) {
                    const int t = lane + 64 * i;
                    bool used = false;
                    for (int q = 0; q < k; ++q) used |= (sel[q] == t);
                    if (!used && e[i] > bv) { bv = e[i]; bi = t; }
                }
#pragma unroll
                for (int off = 32; off >= 1; off >>= 1) {
                    const double ov = __shfl_xor(bv, off);
                    const int    oi = __shfl_xor(bi, off);
                    if (ov > bv || (ov == bv && oi < bi)) { bv = ov; bi = oi; }
                }
                sel[k] = bi;
                if (lane == 0) {
                    out_p[tok * TOPK + k] = (float)(bv * invZ);
                    const int* cp = conn + bi * 3;
                    out_n[(tok * TOPK + k) * 3 + 0] = (float)cp[0];
                    out_n[(tok * TOPK + k) * 3 + 1] = (float)cp[1];
                    out_n[(tok * TOPK + k) * 3 + 2] = (float)cp[2];
                }
            }
        }
        __syncthreads();
    }
}

extern "C" void kernel_launch(void* const* d_in, const int* in_sizes, int n_in,
                              void* d_out, int out_size, void* d_ws, size_t ws_size,
                              hipStream_t stream) {
    const float* x    = (const float*)d_in[0];
    const float* Wr   = (const float*)d_in[1];
    const float* br   = (const float*)d_in[2];
    const int*   conn = (const int*)d_in[3];

    float* out_x = (float*)d_out;
    float* out_p = out_x + (size_t)8 * 4096 * 2048;
    float* out_n = out_p + (size_t)8 * 4096 * 8;

    unsigned*       cnt   = (unsigned*)d_ws;
    unsigned*       list  = (unsigned*)((char*)d_ws + WS_LIST_OFF);
    unsigned short* wt_hi = (unsigned short*)((char*)d_ws + WS_WTHI_OFF);
    unsigned short* wt_lo = (unsigned short*)((char*)d_ws + WS_WTLO_OFF);

    hipLaunchKernelGGL(prep_wt, dim3(32, 4), dim3(256), 0, stream,
                       Wr, cnt, wt_hi, wt_lo);

    static bool attr_set = false;
    if (!attr_set) {
        hipFuncSetAttribute((const void*)router_mfma,
                            hipFuncAttributeMaxDynamicSharedMemorySize, 131072);
        attr_set = true;
    }
    hipLaunchKernelGGL(router_mfma, dim3(32768 / BM), dim3(512), 131072, stream,
                       x, wt_hi, wt_lo, br, conn, out_x, out_p, out_n, cnt, list);

    hipLaunchKernelGGL(refine_fp64, dim3(256), dim3(256), 0, stream,
                       x, Wr, br, conn, out_p, out_n, cnt, list);
}

// Round 4
// 782.675 us; speedup vs baseline: 1.7044x; 1.4971x over previous
//
#include <hip/hip_runtime.h>
#include <math.h>

#define D_DIM 2048
#define T_N   245
#define TOPK  8
#define BM    64
#define NKS   (D_DIM / 32)    // 64 k-steps of 32

typedef __attribute__((ext_vector_type(8))) __bf16 bf16x8;
typedef __attribute__((ext_vector_type(4))) float  f32x4;

// ws layout (~2.3 MB):
//   [0]        : unsigned counter
//   [256]      : token list, unsigned[32768] (128 KB)
//   [256K]     : WT_hi bf16 [256][2048] (1 MB)
//   [256K+1M]  : WT_lo bf16 [256][2048] (1 MB)
#define WS_LIST_OFF   256
#define WS_WTHI_OFF   (256 * 1024)
#define WS_WTLO_OFF   (256 * 1024 + 1024 * 1024)

__device__ __forceinline__ unsigned short bf16_rne(float f) {
    unsigned u = __builtin_bit_cast(unsigned, f);
    u += 0x7FFFu + ((u >> 16) & 1u);
    return (unsigned short)(u >> 16);
}
__device__ __forceinline__ float bf16_to_f(unsigned short h) {
    return __builtin_bit_cast(float, (unsigned)h << 16);
}

// ---------------------------------------------------------------------------
// Prep: W [2048][245] fp32 -> WT_hi/WT_lo [256][2048] bf16 (transposed, split
// hi/lo, cols 245..255 zero). Also zeroes the flag counter.
// ---------------------------------------------------------------------------
__global__ __launch_bounds__(256)
void prep_wt(const float* __restrict__ W,
             unsigned* __restrict__ cnt,
             unsigned short* __restrict__ wt_hi,
             unsigned short* __restrict__ wt_lo)
{
    if (blockIdx.x == 0 && blockIdx.y == 0 && threadIdx.x == 0) *cnt = 0u;

    __shared__ float tile[64][65];
    const int r0 = blockIdx.x * 64;      // k tile (32)
    const int c0 = blockIdx.y * 64;      // n tile (4)
    const int tid = threadIdx.x;
    {
        const int j = tid & 63, ib = tid >> 6;
#pragma unroll
        for (int s = 0; s < 16; ++s) {
            const int i = ib * 16 + s;
            const int c = c0 + j;
            tile[i][j] = (c < T_N) ? W[(long)(r0 + i) * T_N + c] : 0.0f;
        }
    }
    __syncthreads();
    {
        const int ii = tid & 63, jb = tid >> 6;
#pragma unroll
        for (int s = 0; s < 16; ++s) {
            const int jj = jb * 16 + s;
            const float f = tile[ii][jj];
            const unsigned short h = bf16_rne(f);
            const unsigned short l = bf16_rne(f - bf16_to_f(h));
            const long o = (long)(c0 + jj) * D_DIM + (r0 + ii);
            wt_hi[o] = h;
            wt_lo[o] = l;
        }
    }
}

// ---------------------------------------------------------------------------
// Main: LDS-free split-bf16 MFMA GEMM. A/B fragments loaded straight from
// global (fragment layout: row/col = lane&15, k = (lane>>4)*8 + i, verified
// by round-3 pass). LDS used only for the 64x256 epilogue logit buffer ->
// 64 KB -> 2 blocks/CU, 16 waves/CU.
// ---------------------------------------------------------------------------
__device__ __forceinline__ void split8(const float4& A, const float4& B,
                                       bf16x8& h8, bf16x8& l8) {
    const float f[8] = {A.x, A.y, A.z, A.w, B.x, B.y, B.z, B.w};
    unsigned hu[4], lu[4];
#pragma unroll
    for (int p = 0; p < 4; ++p) {
        unsigned short h0 = bf16_rne(f[2 * p]);
        unsigned short h1 = bf16_rne(f[2 * p + 1]);
        unsigned short l0 = bf16_rne(f[2 * p]     - bf16_to_f(h0));
        unsigned short l1 = bf16_rne(f[2 * p + 1] - bf16_to_f(h1));
        hu[p] = (unsigned)h0 | ((unsigned)h1 << 16);
        lu[p] = (unsigned)l0 | ((unsigned)l1 << 16);
    }
    uint4 uh = make_uint4(hu[0], hu[1], hu[2], hu[3]);
    uint4 ul = make_uint4(lu[0], lu[1], lu[2], lu[3]);
    h8 = __builtin_bit_cast(bf16x8, uh);
    l8 = __builtin_bit_cast(bf16x8, ul);
}

__global__ __launch_bounds__(512, 4)
void router_mfma(const float* __restrict__ x,
                 const unsigned short* __restrict__ wt_hi,
                 const unsigned short* __restrict__ wt_lo,
                 const float* __restrict__ br,
                 const int*   __restrict__ conn,
                 float* __restrict__ out_x,
                 float* __restrict__ out_p,
                 float* __restrict__ out_n,
                 unsigned* __restrict__ cnt,
                 unsigned* __restrict__ list)
{
    __shared__ float slog[BM * 256];     // 64 KB

    const int tid  = threadIdx.x;
    const int lane = tid & 63;
    const int wid  = tid >> 6;           // 0..7
    const int wr   = wid >> 2;           // 0..1
    const int wc   = wid & 3;            // 0..3
    const int m16  = lane & 15;
    const int kq   = lane >> 4;          // 0..3
    const long row0 = (long)blockIdx.x * BM;

    const long rowA0 = row0 + wr * 32 + m16;        // fr = 0
    const long rowA1 = rowA0 + 16;                  // fr = 1
    const float* xp0 = x + rowA0 * D_DIM + kq * 8;
    const float* xp1 = x + rowA1 * D_DIM + kq * 8;
    float* op0 = out_x + rowA0 * D_DIM + kq * 8;
    float* op1 = out_x + rowA1 * D_DIM + kq * 8;

    const unsigned short* bh0 = wt_hi + (long)(wc * 64 + m16) * D_DIM + kq * 8;
    const unsigned short* bl0 = wt_lo + (long)(wc * 64 + m16) * D_DIM + kq * 8;

    f32x4 acc[2][4];
#pragma unroll
    for (int fr = 0; fr < 2; ++fr)
#pragma unroll
        for (int fc = 0; fc < 4; ++fc)
            acc[fr][fc] = (f32x4){0.f, 0.f, 0.f, 0.f};

    // prefetch A for step 0
    float4 a0A = *reinterpret_cast<const float4*>(xp0);
    float4 a0B = *reinterpret_cast<const float4*>(xp0 + 4);
    float4 a1A = *reinterpret_cast<const float4*>(xp1);
    float4 a1B = *reinterpret_cast<const float4*>(xp1 + 4);

    for (int ks = 0; ks < NKS; ++ks) {
        const int off = ks * 32;
        // prefetch next step's A
        float4 n0A, n0B, n1A, n1B;
        if (ks + 1 < NKS) {
            n0A = *reinterpret_cast<const float4*>(xp0 + off + 32);
            n0B = *reinterpret_cast<const float4*>(xp0 + off + 36);
            n1A = *reinterpret_cast<const float4*>(xp1 + off + 32);
            n1B = *reinterpret_cast<const float4*>(xp1 + off + 36);
        }
        // x passthrough from the same registers (each (row,k) owned once per wr-group)
        if (wc == 0) {
            *reinterpret_cast<float4*>(op0 + off)     = a0A;
            *reinterpret_cast<float4*>(op0 + off + 4) = a0B;
            *reinterpret_cast<float4*>(op1 + off)     = a1A;
            *reinterpret_cast<float4*>(op1 + off + 4) = a1B;
        }
        // convert current A to hi/lo fragments
        bf16x8 ah0, al0, ah1, al1;
        split8(a0A, a0B, ah0, al0);
        split8(a1A, a1B, ah1, al1);
        // B fragments straight from global (bf16, no conversion) + MFMA
#pragma unroll
        for (int fc = 0; fc < 4; ++fc) {
            const long bo = (long)(fc * 16) * D_DIM + off;
            bf16x8 bh = *reinterpret_cast<const bf16x8*>(bh0 + bo);
            bf16x8 bl = *reinterpret_cast<const bf16x8*>(bl0 + bo);
            acc[0][fc] = __builtin_amdgcn_mfma_f32_16x16x32_bf16(ah0, bh, acc[0][fc], 0, 0, 0);
            acc[1][fc] = __builtin_amdgcn_mfma_f32_16x16x32_bf16(ah1, bh, acc[1][fc], 0, 0, 0);
            acc[0][fc] = __builtin_amdgcn_mfma_f32_16x16x32_bf16(al0, bh, acc[0][fc], 0, 0, 0);
            acc[1][fc] = __builtin_amdgcn_mfma_f32_16x16x32_bf16(al1, bh, acc[1][fc], 0, 0, 0);
            acc[0][fc] = __builtin_amdgcn_mfma_f32_16x16x32_bf16(ah0, bl, acc[0][fc], 0, 0, 0);
            acc[1][fc] = __builtin_amdgcn_mfma_f32_16x16x32_bf16(al1 * (__bf16)0 + ah1, bl, acc[1][fc], 0, 0, 0);
        }
        a0A = n0A; a0B = n0B; a1A = n1A; a1B = n1B;
    }

    // ---- epilogue: logits (+bias) -> swizzled LDS ----
#pragma unroll
    for (int fr = 0; fr < 2; ++fr)
#pragma unroll
        for (int fc = 0; fc < 4; ++fc)
#pragma unroll
            for (int r = 0; r < 4; ++r) {
                const int row = wr * 32 + fr * 16 + kq * 4 + r;
                const int col = wc * 64 + fc * 16 + m16;
                float v = acc[fr][fc][r];
                v = (col < T_N) ? v + br[col] : -1e30f;
                slog[row * 256 + ((col + row) & 255)] = v;
            }
    __syncthreads();

    // ---- per-row softmax + top-8 + near-tie flag (one thread per row) ----
    if (tid < BM) {
        const int r = tid;
        const long gr = row0 + r;
        float* base = &slog[r * 256];
        float m0 = -INFINITY, m1 = -INFINITY, m2 = -INFINITY, m3 = -INFINITY;
        for (int t = 0; t < 244; t += 4) {
            m0 = fmaxf(m0, base[(t + 0 + r) & 255]);
            m1 = fmaxf(m1, base[(t + 1 + r) & 255]);
            m2 = fmaxf(m2, base[(t + 2 + r) & 255]);
            m3 = fmaxf(m3, base[(t + 3 + r) & 255]);
        }
        m0 = fmaxf(m0, base[(244 + r) & 255]);
        const float m = fmaxf(fmaxf(m0, m1), fmaxf(m2, m3));
        float s0 = 0.f, s1 = 0.f, s2 = 0.f, s3 = 0.f;
        for (int t = 0; t < 244; t += 4) {
            float e0 = expf(base[(t + 0 + r) & 255] - m); base[(t + 0 + r) & 255] = e0; s0 += e0;
            float e1 = expf(base[(t + 1 + r) & 255] - m); base[(t + 1 + r) & 255] = e1; s1 += e1;
            float e2 = expf(base[(t + 2 + r) & 255] - m); base[(t + 2 + r) & 255] = e2; s2 += e2;
            float e3 = expf(base[(t + 3 + r) & 255] - m); base[(t + 3 + r) & 255] = e3; s3 += e3;
        }
        { float e = expf(base[(244 + r) & 255] - m); base[(244 + r) & 255] = e; s0 += e; }
        const float inv = 1.0f / ((s0 + s1) + (s2 + s3));
        float prev = INFINITY;
        int flag = 0;
#pragma unroll 1
        for (int k = 0; k < TOPK + 1; ++k) {
            float b0 = -1.f, b1 = -1.f, b2 = -1.f, b3 = -1.f;
            int i0 = 0, i1 = 0, i2 = 0, i3 = 0;
            for (int t = 0; t < 244; t += 4) {
                float v0 = base[(t + 0 + r) & 255];
                float v1 = base[(t + 1 + r) & 255];
                float v2 = base[(t + 2 + r) & 255];
                float v3 = base[(t + 3 + r) & 255];
                if (v0 > b0) { b0 = v0; i0 = t; }
                if (v1 > b1) { b1 = v1; i1 = t + 1; }
                if (v2 > b2) { b2 = v2; i2 = t + 2; }
                if (v3 > b3) { b3 = v3; i3 = t + 3; }
            }
            { float v = base[(244 + r) & 255]; if (v > b0) { b0 = v; i0 = 244; } }
            float best = b0; int bi = i0;
            if (b1 > best || (b1 == best && i1 < bi)) { best = b1; bi = i1; }
            if (b2 > best || (b2 == best && i2 < bi)) { best = b2; bi = i2; }
            if (b3 > best || (b3 == best && i3 < bi)) { best = b3; bi = i3; }
            if (best >= prev * 0.9998f) flag = 1;   // logit gap < 2e-4
            prev = best;
            if (k < TOPK) {
                base[(bi + r) & 255] = -1.f;
                out_p[gr * TOPK + k] = best * inv;
                const int* cp = conn + bi * 3;
                out_n[(gr * TOPK + k) * 3 + 0] = (float)cp[0];
                out_n[(gr * TOPK + k) * 3 + 1] = (float)cp[1];
                out_n[(gr * TOPK + k) * 3 + 2] = (float)cp[2];
            }
        }
        if (flag) {
            unsigned idx = atomicAdd(cnt, 1u);
            if (idx < 32768u) list[idx] = (unsigned)gr;
        }
    }
}

// ---------------------------------------------------------------------------
// Refine: fp64 recompute for flagged tokens. W staged in 64-row LDS chunks
// with coalesced float4 loads (BW-bound, not latency-bound); 4 tokens/block
// share the staged chunk; wave-parallel softmax+top-8.
// ---------------------------------------------------------------------------
#define RB 4
#define LDSW 248
__global__ __launch_bounds__(256)
void refine_fp64(const float* __restrict__ x,
                 const float* __restrict__ W,
                 const float* __restrict__ br,
                 const int*   __restrict__ conn,
                 float* __restrict__ out_p,
                 float* __restrict__ out_n,
                 const unsigned* __restrict__ cnt,
                 const unsigned* __restrict__ list)
{
    __shared__ float  sx[RB][D_DIM];    // 32 KB
    __shared__ float  sw[65][LDSW];     // 64.5 KB
    __shared__ double sl[RB][256];      // 8 KB

    const int tid = threadIdx.x;
    const unsigned count = min(*cnt, 32768u);

    for (unsigned b0 = blockIdx.x * RB; b0 < count; b0 += gridDim.x * RB) {
        const int nb = (int)min((unsigned)RB, count - b0);
#pragma unroll
        for (int j = 0; j < RB; ++j) {
            if (j < nb) {
                const long tok = (long)list[b0 + j];
                const float4* src = reinterpret_cast<const float4*>(x + tok * D_DIM);
                for (int i = tid; i < D_DIM / 4; i += 256)
                    *reinterpret_cast<float4*>(&sx[j][i * 4]) = src[i];
            } else {
                for (int i = tid; i < D_DIM / 4; i += 256)
                    *reinterpret_cast<float4*>(&sx[j][i * 4]) = make_float4(0.f, 0.f, 0.f, 0.f);
            }
        }

        double a0 = 0.0, a1 = 0.0, a2 = 0.0, a3 = 0.0;
        for (int kc = 0; kc < D_DIM; kc += 64) {
            __syncthreads();   // sw (and first-iter sx) producers/consumers
            // stage W[kc..kc+64)[0..245) coalesced
            const float4* wsrc = reinterpret_cast<const float4*>(W + (long)kc * T_N);
            for (int i4 = tid; i4 < (64 * T_N) / 4; i4 += 256) {
                float4 v = wsrc[i4];
                int flat = i4 * 4;
                int rr = (int)(((unsigned)flat * 68480u) >> 24);   // flat / 245
                int cc = flat - rr * 245;
                float vv[4] = {v.x, v.y, v.z, v.w};
#pragma unroll
                for (int e = 0; e < 4; ++e) {
                    int c2 = cc + e, r2 = rr;
                    if (c2 >= T_N) { c2 -= T_N; r2 += 1; }
                    sw[r2][c2] = vv[e];
                }
            }
            __syncthreads();
            if (tid < T_N) {
                for (int kk = 0; kk < 64; kk += 4) {
                    float4 x0 = *reinterpret_cast<const float4*>(&sx[0][kc + kk]);
                    float4 x1 = *reinterpret_cast<const float4*>(&sx[1][kc + kk]);
                    float4 x2 = *reinterpret_cast<const float4*>(&sx[2][kc + kk]);
                    float4 x3 = *reinterpret_cast<const float4*>(&sx[3][kc + kk]);
                    const float* f0 = reinterpret_cast<const float*>(&x0);
                    const float* f1 = reinterpret_cast<const float*>(&x1);
                    const float* f2 = reinterpret_cast<const float*>(&x2);
                    const float* f3 = reinterpret_cast<const float*>(&x3);
#pragma unroll
                    for (int u = 0; u < 4; ++u) {
                        const double w = (double)sw[kk + u][tid];
                        a0 += (double)f0[u] * w;
                        a1 += (double)f1[u] * w;
                        a2 += (double)f2[u] * w;
                        a3 += (double)f3[u] * w;
                    }
                }
            }
        }
        if (tid < T_N) {
            const double bb = (double)br[tid];
            sl[0][tid] = a0 + bb; sl[1][tid] = a1 + bb;
            sl[2][tid] = a2 + bb; sl[3][tid] = a3 + bb;
        } else {
#pragma unroll
            for (int j = 0; j < RB; ++j) sl[j][tid] = -1.0e300;
        }
        __syncthreads();

        const int w = tid >> 6, lane = tid & 63;
        if (w < nb) {
            const long tok = (long)list[b0 + w];
            double v[4];
#pragma unroll
            for (int i = 0; i < 4; ++i) {
                const int t = lane + 64 * i;
                v[i] = (t < T_N) ? sl[w][t] : -1.0e300;
            }
            double m = fmax(fmax(v[0], v[1]), fmax(v[2], v[3]));
#pragma unroll
            for (int off = 32; off >= 1; off >>= 1)
                m = fmax(m, __shfl_xor(m, off));
            double e[4]; double s = 0.0;
#pragma unroll
            for (int i = 0; i < 4; ++i) {
                const int t = lane + 64 * i;
                e[i] = (t < T_N) ? exp(sl[w][t] - m) : 0.0;
                s += e[i];
            }
#pragma unroll
            for (int off = 32; off >= 1; off >>= 1)
                s += __shfl_xor(s, off);
            const double invZ = 1.0 / s;

            int sel[TOPK];
#pragma unroll 1
            for (int k = 0; k < TOPK; ++k) {
                double bv = -1.0; int bi = 255;
#pragma unroll
                for (int i = 0; i < 4; ++i) {
                    const int t = lane + 64 * i;
                    bool used = false;
                    for (int q = 0; q < k; ++q) used |= (sel[q] == t);
                    if (!used && e[i] > bv) { bv = e[i]; bi = t; }
                }
#pragma unroll
                for (int off = 32; off >= 1; off >>= 1) {
                    const double ov = __shfl_xor(bv, off);
                    const int    oi = __shfl_xor(bi, off);
                    if (ov > bv || (ov == bv && oi < bi)) { bv = ov; bi = oi; }
                }
                sel[k] = bi;
                if (lane == 0) {
                    out_p[tok * TOPK + k] = (float)(bv * invZ);
                    const int* cp = conn + bi * 3;
                    out_n[(tok * TOPK + k) * 3 + 0] = (float)cp[0];
                    out_n[(tok * TOPK + k) * 3 + 1] = (float)cp[1];
                    out_n[(tok * TOPK + k) * 3 + 2] = (float)cp[2];
                }
            }
        }
        __syncthreads();   // protect sx/sl before next group
    }
}

extern "C" void kernel_launch(void* const* d_in, const int* in_sizes, int n_in,
                              void* d_out, int out_size, void* d_ws, size_t ws_size,
                              hipStream_t stream) {
    const float* x    = (const float*)d_in[0];
    const float* Wr   = (const float*)d_in[1];
    const float* br   = (const float*)d_in[2];
    const int*   conn = (const int*)d_in[3];

    float* out_x = (float*)d_out;
    float* out_p = out_x + (size_t)8 * 4096 * 2048;
    float* out_n = out_p + (size_t)8 * 4096 * 8;

    unsigned*       cnt   = (unsigned*)d_ws;
    unsigned*       list  = (unsigned*)((char*)d_ws + WS_LIST_OFF);
    unsigned short* wt_hi = (unsigned short*)((char*)d_ws + WS_WTHI_OFF);
    unsigned short* wt_lo = (unsigned short*)((char*)d_ws + WS_WTLO_OFF);

    hipLaunchKernelGGL(prep_wt, dim3(32, 4), dim3(256), 0, stream,
                       Wr, cnt, wt_hi, wt_lo);
    hipLaunchKernelGGL(router_mfma, dim3(32768 / BM), dim3(512), 0, stream,
                       x, wt_hi, wt_lo, br, conn, out_x, out_p, out_n, cnt, list);
    hipLaunchKernelGGL(refine_fp64, dim3(256), dim3(256), 0, stream,
                       x, Wr, br, conn, out_p, out_n, cnt, list);
}

// Round 5
// 666.415 us; speedup vs baseline: 2.0018x; 1.1745x over previous
//
#include <hip/hip_runtime.h>
#include <math.h>

#define D_DIM 2048
#define T_N   245
#define TOPK  8
#define BM    64
#define NCH   32              // 2048 / 64

typedef __attribute__((ext_vector_type(8))) __bf16 bf16x8;
typedef __attribute__((ext_vector_type(4))) float  f32x4;

// ws layout (~2.3 MB):
//   [0]        : unsigned counter
//   [256]      : token list, unsigned[32768] (128 KB)
//   [256K]     : WT_hi bf16 [256][2048] (1 MB)
//   [256K+1M]  : WT_lo bf16 [256][2048] (1 MB)
#define WS_LIST_OFF   256
#define WS_WTHI_OFF   (256 * 1024)
#define WS_WTLO_OFF   (256 * 1024 + 1024 * 1024)

__device__ __forceinline__ unsigned short bf16_rne(float f) {
    unsigned u = __builtin_bit_cast(unsigned, f);
    u += 0x7FFFu + ((u >> 16) & 1u);
    return (unsigned short)(u >> 16);
}
__device__ __forceinline__ float bf16_to_f(unsigned short h) {
    return __builtin_bit_cast(float, (unsigned)h << 16);
}

// async global->LDS, 16 B per lane; LDS dest = wave-uniform base + lane*16
__device__ __forceinline__ void gll16(const float* g, float* l) {
    __builtin_amdgcn_global_load_lds(
        (const __attribute__((address_space(1))) void*)g,
        (__attribute__((address_space(3))) void*)l, 16, 0, 0);
}

__device__ __forceinline__ void split8(const float4& A, const float4& B,
                                       bf16x8& h8, bf16x8& l8) {
    const float f[8] = {A.x, A.y, A.z, A.w, B.x, B.y, B.z, B.w};
    unsigned hu[4], lu[4];
#pragma unroll
    for (int p = 0; p < 4; ++p) {
        unsigned short h0 = bf16_rne(f[2 * p]);
        unsigned short h1 = bf16_rne(f[2 * p + 1]);
        unsigned short l0 = bf16_rne(f[2 * p]     - bf16_to_f(h0));
        unsigned short l1 = bf16_rne(f[2 * p + 1] - bf16_to_f(h1));
        hu[p] = (unsigned)h0 | ((unsigned)h1 << 16);
        lu[p] = (unsigned)l0 | ((unsigned)l1 << 16);
    }
    uint4 uh = make_uint4(hu[0], hu[1], hu[2], hu[3]);
    uint4 ul = make_uint4(lu[0], lu[1], lu[2], lu[3]);
    h8 = __builtin_bit_cast(bf16x8, uh);
    l8 = __builtin_bit_cast(bf16x8, ul);
}

// ---------------------------------------------------------------------------
// Prep: W [2048][245] fp32 -> WT_hi/WT_lo [256][2048] bf16 (transposed, split
// hi/lo, cols 245..255 zero). Also zeroes the flag counter.
// ---------------------------------------------------------------------------
__global__ __launch_bounds__(256)
void prep_wt(const float* __restrict__ W,
             unsigned* __restrict__ cnt,
             unsigned short* __restrict__ wt_hi,
             unsigned short* __restrict__ wt_lo)
{
    if (blockIdx.x == 0 && blockIdx.y == 0 && threadIdx.x == 0) *cnt = 0u;

    __shared__ float tile[64][65];
    const int r0 = blockIdx.x * 64;      // k tile (32)
    const int c0 = blockIdx.y * 64;      // n tile (4)
    const int tid = threadIdx.x;
    {
        const int j = tid & 63, ib = tid >> 6;
#pragma unroll
        for (int s = 0; s < 16; ++s) {
            const int i = ib * 16 + s;
            const int c = c0 + j;
            tile[i][j] = (c < T_N) ? W[(long)(r0 + i) * T_N + c] : 0.0f;
        }
    }
    __syncthreads();
    {
        const int ii = tid & 63, jb = tid >> 6;
#pragma unroll
        for (int s = 0; s < 16; ++s) {
            const int jj = jb * 16 + s;
            const float f = tile[ii][jj];
            const unsigned short h = bf16_rne(f);
            const unsigned short l = bf16_rne(f - bf16_to_f(h));
            const long o = (long)(c0 + jj) * D_DIM + (r0 + ii);
            wt_hi[o] = h;
            wt_lo[o] = l;
        }
    }
}

// ---------------------------------------------------------------------------
// Main router: global_load_lds double-buffered x staging (pre-swizzled source,
// XOR-swizzled reads), split-bf16 MFMA, out_x passthrough from LDS, fused
// softmax/top-8 epilogue.  256 thr (4 waves = 4 col-quarters), 64 KB LDS.
// LDS tile layout: [64 rows][16 units of 16B]; phys unit = u ^ (row & 15).
// ---------------------------------------------------------------------------
__global__ __launch_bounds__(256, 2)
void router_mfma(const float* __restrict__ x,
                 const unsigned short* __restrict__ wt_hi,
                 const unsigned short* __restrict__ wt_lo,
                 const float* __restrict__ br,
                 const int*   __restrict__ conn,
                 float* __restrict__ out_x,
                 float* __restrict__ out_p,
                 float* __restrict__ out_n,
                 unsigned* __restrict__ cnt,
                 unsigned* __restrict__ list)
{
    __shared__ float smem[16384];        // xbuf[2][64][64] floats / slog[64][256]

    const int tid  = threadIdx.x;
    const int lane = tid & 63;
    const int w    = tid >> 6;           // wave id == col-quarter (0..3)
    const int m16  = lane & 15;
    const int kq   = lane >> 4;          // 0..3
    const long row0 = (long)blockIdx.x * BM;

    f32x4 acc[4][4];
#pragma unroll
    for (int fr = 0; fr < 4; ++fr)
#pragma unroll
        for (int fc = 0; fc < 4; ++fc)
            acc[fr][fc] = (f32x4){0.f, 0.f, 0.f, 0.f};

    // ---- prologue: stage chunk 0 into buf 0 ----
#pragma unroll
    for (int q = 0; q < 4; ++q) {
        const int rl = w * 16 + q * 4 + (lane >> 4);
        const int u  = (lane & 15) ^ (rl & 15);
        gll16(x + (row0 + rl) * (long)D_DIM + u * 4,
              &smem[(w * 16 + q * 4) * 64]);
    }
    __syncthreads();   // drains vmcnt -> buf0 ready

    for (int c = 0; c < NCH; ++c) {
        const int k0   = c * 64;
        const int bufF = (c & 1) * 4096;

        // ---- issue next chunk's staging (async, stays in flight) ----
        if (c + 1 < NCH) {
            const int nbF = ((c + 1) & 1) * 4096;
#pragma unroll
            for (int q = 0; q < 4; ++q) {
                const int rl = w * 16 + q * 4 + (lane >> 4);
                const int u  = (lane & 15) ^ (rl & 15);
                gll16(x + (row0 + rl) * (long)D_DIM + (k0 + 64) + u * 4,
                      &smem[nbF + (w * 16 + q * 4) * 64]);
            }
        }

        // ---- B fragments for this chunk (L2-resident, hidden under below) ----
        uint4 bh[4][2], bl[4][2];
#pragma unroll
        for (int fc = 0; fc < 4; ++fc)
#pragma unroll
            for (int ks = 0; ks < 2; ++ks) {
                const long bo = (long)(w * 64 + fc * 16 + m16) * D_DIM
                                + k0 + ks * 32 + kq * 8;
                bh[fc][ks] = *reinterpret_cast<const uint4*>(wt_hi + bo);
                bl[fc][ks] = *reinterpret_cast<const uint4*>(wt_lo + bo);
            }

        // ---- x passthrough for this chunk from LDS ----
        {
            const int row = tid >> 2;
            const int ub  = (tid & 3) * 4;
            float4 vv[4];
#pragma unroll
            for (int j = 0; j < 4; ++j)
                vv[j] = *reinterpret_cast<const float4*>(
                    &smem[bufF + row * 64 + ((ub + j) ^ (row & 15)) * 4]);
#pragma unroll
            for (int j = 0; j < 4; ++j)
                *reinterpret_cast<float4*>(
                    out_x + (row0 + row) * (long)D_DIM + k0 + (ub + j) * 4) = vv[j];
        }

        // ---- compute: 2 k-steps x 3 passes (hi*hi, lo*hi, hi*lo) ----
#pragma unroll
        for (int ks = 0; ks < 2; ++ks) {
            bf16x8 ah[4], al[4];
#pragma unroll
            for (int fr = 0; fr < 4; ++fr) {
                const int row = fr * 16 + m16;          // row & 15 == m16
                const int u0  = ks * 8 + kq * 2;
                float4 r0 = *reinterpret_cast<const float4*>(
                    &smem[bufF + row * 64 + ((u0)     ^ m16) * 4]);
                float4 r1 = *reinterpret_cast<const float4*>(
                    &smem[bufF + row * 64 + ((u0 + 1) ^ m16) * 4]);
                split8(r0, r1, ah[fr], al[fr]);
            }
#pragma unroll
            for (int fc = 0; fc < 4; ++fc) {
                const bf16x8 bhv = __builtin_bit_cast(bf16x8, bh[fc][ks]);
                const bf16x8 blv = __builtin_bit_cast(bf16x8, bl[fc][ks]);
#pragma unroll
                for (int fr = 0; fr < 4; ++fr) {
                    acc[fr][fc] = __builtin_amdgcn_mfma_f32_16x16x32_bf16(ah[fr], bhv, acc[fr][fc], 0, 0, 0);
                    acc[fr][fc] = __builtin_amdgcn_mfma_f32_16x16x32_bf16(al[fr], bhv, acc[fr][fc], 0, 0, 0);
                    acc[fr][fc] = __builtin_amdgcn_mfma_f32_16x16x32_bf16(ah[fr], blv, acc[fr][fc], 0, 0, 0);
                }
            }
        }
        __syncthreads();   // drains gll(c+1) + orders buffer reuse
    }

    // ---- epilogue: logits (+bias) -> swizzled slog (reuses smem) ----
#pragma unroll
    for (int fr = 0; fr < 4; ++fr)
#pragma unroll
        for (int fc = 0; fc < 4; ++fc)
#pragma unroll
            for (int r = 0; r < 4; ++r) {
                const int row = fr * 16 + kq * 4 + r;
                const int col = w * 64 + fc * 16 + m16;
                float v = acc[fr][fc][r];
                v = (col < T_N) ? v + br[col] : -1e30f;
                smem[row * 256 + ((col + row) & 255)] = v;
            }
    __syncthreads();

    // ---- per-row softmax + top-8 + near-tie flag (one thread per row) ----
    if (tid < BM) {
        const int r = tid;
        const long gr = row0 + r;
        float* base = &smem[r * 256];
        float m0 = -INFINITY, m1 = -INFINITY, m2 = -INFINITY, m3 = -INFINITY;
        for (int t = 0; t < 244; t += 4) {
            m0 = fmaxf(m0, base[(t + 0 + r) & 255]);
            m1 = fmaxf(m1, base[(t + 1 + r) & 255]);
            m2 = fmaxf(m2, base[(t + 2 + r) & 255]);
            m3 = fmaxf(m3, base[(t + 3 + r) & 255]);
        }
        m0 = fmaxf(m0, base[(244 + r) & 255]);
        const float m = fmaxf(fmaxf(m0, m1), fmaxf(m2, m3));
        float s0 = 0.f, s1 = 0.f, s2 = 0.f, s3 = 0.f;
        for (int t = 0; t < 244; t += 4) {
            float e0 = expf(base[(t + 0 + r) & 255] - m); base[(t + 0 + r) & 255] = e0; s0 += e0;
            float e1 = expf(base[(t + 1 + r) & 255] - m); base[(t + 1 + r) & 255] = e1; s1 += e1;
            float e2 = expf(base[(t + 2 + r) & 255] - m); base[(t + 2 + r) & 255] = e2; s2 += e2;
            float e3 = expf(base[(t + 3 + r) & 255] - m); base[(t + 3 + r) & 255] = e3; s3 += e3;
        }
        { float e = expf(base[(244 + r) & 255] - m); base[(244 + r) & 255] = e; s0 += e; }
        const float inv = 1.0f / ((s0 + s1) + (s2 + s3));
        float prev = INFINITY;
        int flag = 0;
#pragma unroll 1
        for (int k = 0; k < TOPK + 1; ++k) {
            float b0 = -1.f, b1 = -1.f, b2 = -1.f, b3 = -1.f;
            int i0 = 0, i1 = 0, i2 = 0, i3 = 0;
            for (int t = 0; t < 244; t += 4) {
                float v0 = base[(t + 0 + r) & 255];
                float v1 = base[(t + 1 + r) & 255];
                float v2 = base[(t + 2 + r) & 255];
                float v3 = base[(t + 3 + r) & 255];
                if (v0 > b0) { b0 = v0; i0 = t; }
                if (v1 > b1) { b1 = v1; i1 = t + 1; }
                if (v2 > b2) { b2 = v2; i2 = t + 2; }
                if (v3 > b3) { b3 = v3; i3 = t + 3; }
            }
            { float v = base[(244 + r) & 255]; if (v > b0) { b0 = v; i0 = 244; } }
            float best = b0; int bi = i0;
            if (b1 > best || (b1 == best && i1 < bi)) { best = b1; bi = i1; }
            if (b2 > best || (b2 == best && i2 < bi)) { best = b2; bi = i2; }
            if (b3 > best || (b3 == best && i3 < bi)) { best = b3; bi = i3; }
            if (best >= prev * 0.9998f) flag = 1;   // logit gap < 2e-4
            prev = best;
            if (k < TOPK) {
                base[(bi + r) & 255] = -1.f;
                out_p[gr * TOPK + k] = best * inv;
                const int* cp = conn + bi * 3;
                out_n[(gr * TOPK + k) * 3 + 0] = (float)cp[0];
                out_n[(gr * TOPK + k) * 3 + 1] = (float)cp[1];
                out_n[(gr * TOPK + k) * 3 + 2] = (float)cp[2];
            }
        }
        if (flag) {
            unsigned idx = atomicAdd(cnt, 1u);
            if (idx < 32768u) list[idx] = (unsigned)gr;
        }
    }
}

// ---------------------------------------------------------------------------
// Refine: fp64 recompute for flagged tokens, one token per block-iteration.
// 4 waves split K (512 each); lane covers 4 cols; scalar W loads (245-stride
// is not 16B-alignable); cross-wave combine in LDS; wave-0 shuffle top-k.
// ---------------------------------------------------------------------------
__global__ __launch_bounds__(256)
void refine_fp64(const float* __restrict__ x,
                 const float* __restrict__ W,
                 const float* __restrict__ br,
                 const int*   __restrict__ conn,
                 float* __restrict__ out_p,
                 float* __restrict__ out_n,
                 const unsigned* __restrict__ cnt,
                 const unsigned* __restrict__ list)
{
    __shared__ float  sx[D_DIM];        // 8 KB
    __shared__ double sacc[4][248];     // 7.75 KB
    __shared__ double slog[256];        // 2 KB

    const int tid = threadIdx.x, w = tid >> 6, lane = tid & 63;
    const unsigned count = min(*cnt, 32768u);

    for (unsigned it = blockIdx.x; it < count; it += gridDim.x) {
        const long tok = (long)list[it];
        // stage x row
        for (int i = tid; i < D_DIM / 4; i += 256)
            *reinterpret_cast<float4*>(&sx[i * 4]) =
                *reinterpret_cast<const float4*>(x + tok * D_DIM + i * 4);
        __syncthreads();

        // partial dot products: wave w covers k in [w*512, w*512+512)
        double a0 = 0.0, a1 = 0.0, a2 = 0.0, a3 = 0.0;
        const int c0 = lane * 4;
        const int kb = w * 512;
        if (c0 < T_N) {
            const bool full = (c0 + 3 < T_N);
#pragma unroll 4
            for (int k = 0; k < 512; ++k) {
                const double xv = (double)sx[kb + k];
                const float* wp = W + (long)(kb + k) * T_N + c0;
                if (full) {
                    a0 += xv * (double)wp[0];
                    a1 += xv * (double)wp[1];
                    a2 += xv * (double)wp[2];
                    a3 += xv * (double)wp[3];
                } else {
                    a0 += xv * (double)wp[0];   // c0 == 244 only
                }
            }
        }
        if (c0 < T_N) {
            sacc[w][c0] = a0;
            if (c0 + 3 < T_N) {
                sacc[w][c0 + 1] = a1; sacc[w][c0 + 2] = a2; sacc[w][c0 + 3] = a3;
            }
        }
        __syncthreads();

        slog[tid] = (tid < T_N)
            ? sacc[0][tid] + sacc[1][tid] + sacc[2][tid] + sacc[3][tid] + (double)br[tid]
            : -1.0e300;
        __syncthreads();

        if (w == 0) {
            double v[4];
#pragma unroll
            for (int i = 0; i < 4; ++i) v[i] = slog[lane + 64 * i];
            double m = fmax(fmax(v[0], v[1]), fmax(v[2], v[3]));
#pragma unroll
            for (int off = 32; off >= 1; off >>= 1)
                m = fmax(m, __shfl_xor(m, off));
            double e[4]; double s = 0.0;
#pragma unroll
            for (int i = 0; i < 4; ++i) {
                const int t = lane + 64 * i;
                e[i] = (t < T_N) ? exp(slog[t] - m) : 0.0;
                s += e[i];
            }
#pragma unroll
            for (int off = 32; off >= 1; off >>= 1)
                s += __shfl_xor(s, off);
            const double invZ = 1.0 / s;

            int sel[TOPK];
#pragma unroll 1
            for (int k = 0; k < TOPK; ++k) {
                double bv = -1.0; int bi = 255;
#pragma unroll
                for (int i = 0; i < 4; ++i) {
                    const int t = lane + 64 * i;
                    bool used = false;
                    for (int q = 0; q < k; ++q) used |= (sel[q] == t);
                    if (!used && e[i] > bv) { bv = e[i]; bi = t; }
                }
#pragma unroll
                for (int off = 32; off >= 1; off >>= 1) {
                    const double ov = __shfl_xor(bv, off);
                    const int    oi = __shfl_xor(bi, off);
                    if (ov > bv || (ov == bv && oi < bi)) { bv = ov; bi = oi; }
                }
                sel[k] = bi;
                if (lane == 0) {
                    out_p[tok * TOPK + k] = (float)(bv * invZ);
                    const int* cp = conn + bi * 3;
                    out_n[(tok * TOPK + k) * 3 + 0] = (float)cp[0];
                    out_n[(tok * TOPK + k) * 3 + 1] = (float)cp[1];
                    out_n[(tok * TOPK + k) * 3 + 2] = (float)cp[2];
                }
            }
        }
        __syncthreads();
    }
}

extern "C" void kernel_launch(void* const* d_in, const int* in_sizes, int n_in,
                              void* d_out, int out_size, void* d_ws, size_t ws_size,
                              hipStream_t stream) {
    const float* x    = (const float*)d_in[0];
    const float* Wr   = (const float*)d_in[1];
    const float* br   = (const float*)d_in[2];
    const int*   conn = (const int*)d_in[3];

    float* out_x = (float*)d_out;
    float* out_p = out_x + (size_t)8 * 4096 * 2048;
    float* out_n = out_p + (size_t)8 * 4096 * 8;

    unsigned*       cnt   = (unsigned*)d_ws;
    unsigned*       list  = (unsigned*)((char*)d_ws + WS_LIST_OFF);
    unsigned short* wt_hi = (unsigned short*)((char*)d_ws + WS_WTHI_OFF);
    unsigned short* wt_lo = (unsigned short*)((char*)d_ws + WS_WTLO_OFF);

    hipLaunchKernelGGL(prep_wt, dim3(32, 4), dim3(256), 0, stream,
                       Wr, cnt, wt_hi, wt_lo);
    hipLaunchKernelGGL(router_mfma, dim3(32768 / BM), dim3(256), 0, stream,
                       x, wt_hi, wt_lo, br, conn, out_x, out_p, out_n, cnt, list);
    hipLaunchKernelGGL(refine_fp64, dim3(512), dim3(256), 0, stream,
                       x, Wr, br, conn, out_p, out_n, cnt, list);
}